// Round 1
// baseline (119.677 us; speedup 1.0000x reference)
//
#include <hip/hip_runtime.h>

#define B_N 32768
#define H_N 768
#define L_N 10
#define SPB 64                 // samples per block
#define NCHUNK 4               // H chunks (one per wave)
#define CH (H_N / NCHUNK)      // 192 elements per chunk

__global__ __launch_bounds__(256) void ce_fused(
    const float* __restrict__ hs,
    const float* __restrict__ w1, const float* __restrict__ b1v,
    const float* __restrict__ w2, const float* __restrict__ b2v,
    const float* __restrict__ w3, const float* __restrict__ b3v,
    const int* __restrict__ groups, const int* __restrict__ labels,
    float* __restrict__ out)
{
    __shared__ float part[NCHUNK][SPB][L_N];   // 10,240 B

    const int t     = threadIdx.x;
    const int lane  = t & 63;
    const int chunk = t >> 6;                  // wave id = H-chunk id
    const int s     = blockIdx.x * SPB + lane; // sample id

    const float* hrow = hs + (size_t)s * H_N + chunk * CH;
    const float* wp1  = w1 + chunk * CH;
    const float* wp2  = w2 + chunk * CH;
    const float* wp3  = w3 + chunk * CH;

    float acc0[L_N], acc1[L_N], acc2[L_N];
    #pragma unroll
    for (int l = 0; l < L_N; ++l) { acc0[l] = 0.f; acc1[l] = 0.f; acc2[l] = 0.f; }

    // Inner loop: h float4 per lane (each lane streams its own row-chunk);
    // weight addresses are wave-uniform -> scalar/broadcast loads, L2-resident.
    #pragma unroll 2
    for (int k = 0; k < CH; k += 4) {
        const float4 h4 = *reinterpret_cast<const float4*>(hrow + k);
        #pragma unroll
        for (int l = 0; l < L_N; ++l) {
            const float4 a = *reinterpret_cast<const float4*>(wp1 + l * H_N + k);
            const float4 b = *reinterpret_cast<const float4*>(wp2 + l * H_N + k);
            const float4 c = *reinterpret_cast<const float4*>(wp3 + l * H_N + k);
            acc0[l] += h4.x * a.x + h4.y * a.y + h4.z * a.z + h4.w * a.w;
            acc1[l] += h4.x * b.x + h4.y * b.y + h4.z * b.z + h4.w * b.w;
            acc2[l] += h4.x * c.x + h4.y * c.y + h4.z * c.z + h4.w * c.w;
        }
    }

    // Select this sample's group with compile-time indices (no runtime array
    // indexing -> no scratch), stash chunk-partials in LDS.
    const int g = groups[s];
    #pragma unroll
    for (int l = 0; l < L_N; ++l) {
        float v = (g == 0) ? acc0[l] : ((g == 1) ? acc1[l] : acc2[l]);
        part[chunk][lane][l] = v;
    }
    __syncthreads();

    // Wave 0: combine chunks, add bias, log-softmax, NLL, reduce.
    float nll = 0.f;
    if (t < SPB) {
        const int gg = groups[s];  // s == blockIdx.x*64 + t here
        const float* bp = (gg == 0) ? b1v : ((gg == 1) ? b2v : b3v);
        float logit[L_N];
        #pragma unroll
        for (int l = 0; l < L_N; ++l) {
            logit[l] = part[0][t][l] + part[1][t][l] + part[2][t][l] +
                       part[3][t][l] + bp[l];
        }
        float m = logit[0];
        #pragma unroll
        for (int l = 1; l < L_N; ++l) m = fmaxf(m, logit[l]);
        float sum = 0.f;
        #pragma unroll
        for (int l = 0; l < L_N; ++l) sum += expf(logit[l] - m);
        const int lab = labels[s];
        float sel = logit[0];
        #pragma unroll
        for (int l = 1; l < L_N; ++l) sel = (lab == l) ? logit[l] : sel;
        nll = (m + logf(sum)) - sel;
    }
    if (t < 64) {
        #pragma unroll
        for (int off = 32; off > 0; off >>= 1)
            nll += __shfl_down(nll, off, 64);
        if (t == 0) atomicAdd(out, nll * (1.0f / (float)B_N));
    }
}

extern "C" void kernel_launch(void* const* d_in, const int* in_sizes, int n_in,
                              void* d_out, int out_size, void* d_ws, size_t ws_size,
                              hipStream_t stream) {
    const float* hs  = (const float*)d_in[0];
    const float* w1  = (const float*)d_in[1];
    const float* b1v = (const float*)d_in[2];
    const float* w2  = (const float*)d_in[3];
    const float* b2v = (const float*)d_in[4];
    const float* w3  = (const float*)d_in[5];
    const float* b3v = (const float*)d_in[6];
    const int* groups = (const int*)d_in[7];
    const int* labels = (const int*)d_in[8];
    float* out = (float*)d_out;

    hipMemsetAsync(out, 0, sizeof(float), stream);
    ce_fused<<<B_N / SPB, 256, 0, stream>>>(hs, w1, b1v, w2, b2v, w3, b3v,
                                            groups, labels, out);
}

// Round 2
// 70.994 us; speedup vs baseline: 1.6857x; 1.6857x over previous
//
#include <hip/hip_runtime.h>

#define B_N 32768
#define H_N 768
#define L_N 10
#define SPB 64                  // samples per block (= lanes per wave)
#define NCHUNK 8                // K-chunks, one per wave
#define CH (H_N / NCHUNK)       // 96 floats per chunk
#define TPB (SPB * NCHUNK / 8 * 8)  // 512 threads

__global__ __launch_bounds__(512, 4) void ce_fused(
    const float* __restrict__ hs,
    const float* __restrict__ w1, const float* __restrict__ b1v,
    const float* __restrict__ w2, const float* __restrict__ b2v,
    const float* __restrict__ w3, const float* __restrict__ b3v,
    const int* __restrict__ groups, const int* __restrict__ labels,
    float* __restrict__ out)
{
    __shared__ float part[NCHUNK][SPB][L_N];   // 20,480 B

    const int t    = threadIdx.x;
    const int lane = t & 63;
    // Wave-uniform chunk id, made provably uniform so weight loads scalarize
    // to s_load (constant-cache pipe), freeing the vector-memory pipe.
    const int chunk = __builtin_amdgcn_readfirstlane(t >> 6);
    const int s     = blockIdx.x * SPB + lane;  // sample id

    const float* hrow = hs + (size_t)s * H_N + chunk * CH;
    const float* wp1  = w1 + chunk * CH;   // SGPR-based pointers
    const float* wp2  = w2 + chunk * CH;
    const float* wp3  = w3 + chunk * CH;

    float acc0[L_N], acc1[L_N], acc2[L_N];
    #pragma unroll
    for (int l = 0; l < L_N; ++l) { acc0[l] = 0.f; acc1[l] = 0.f; acc2[l] = 0.f; }

    #pragma unroll 2
    for (int k = 0; k < CH; k += 4) {
        const float4 h4 = *reinterpret_cast<const float4*>(hrow + k);
        #pragma unroll
        for (int l = 0; l < L_N; ++l) {
            const float4 a = *reinterpret_cast<const float4*>(wp1 + l * H_N + k);
            const float4 b = *reinterpret_cast<const float4*>(wp2 + l * H_N + k);
            const float4 c = *reinterpret_cast<const float4*>(wp3 + l * H_N + k);
            acc0[l] += h4.x * a.x + h4.y * a.y + h4.z * a.z + h4.w * a.w;
            acc1[l] += h4.x * b.x + h4.y * b.y + h4.z * b.z + h4.w * b.w;
            acc2[l] += h4.x * c.x + h4.y * c.y + h4.z * c.z + h4.w * c.w;
        }
    }

    // Per-sample group select with compile-time indices (no scratch), then
    // stash this chunk's partial logits.
    const int g = groups[s];
    #pragma unroll
    for (int l = 0; l < L_N; ++l) {
        float v = (g == 0) ? acc0[l] : ((g == 1) ? acc1[l] : acc2[l]);
        part[chunk][lane][l] = v;
    }
    __syncthreads();

    // Wave 0: combine 8 chunk-partials, bias, log-softmax, NLL, reduce.
    float nll = 0.f;
    if (t < SPB) {
        const int gg = groups[s];  // s == blockIdx.x*64 + t for wave 0
        const float* bp = (gg == 0) ? b1v : ((gg == 1) ? b2v : b3v);
        float logit[L_N];
        #pragma unroll
        for (int l = 0; l < L_N; ++l) {
            float v = bp[l];
            #pragma unroll
            for (int c = 0; c < NCHUNK; ++c) v += part[c][t][l];
            logit[l] = v;
        }
        float m = logit[0];
        #pragma unroll
        for (int l = 1; l < L_N; ++l) m = fmaxf(m, logit[l]);
        float sum = 0.f;
        #pragma unroll
        for (int l = 0; l < L_N; ++l) sum += expf(logit[l] - m);
        const int lab = labels[s];
        float sel = logit[0];
        #pragma unroll
        for (int l = 1; l < L_N; ++l) sel = (lab == l) ? logit[l] : sel;
        nll = (m + logf(sum)) - sel;
    }
    if (t < 64) {
        #pragma unroll
        for (int off = 32; off > 0; off >>= 1)
            nll += __shfl_down(nll, off, 64);
        if (t == 0) atomicAdd(out, nll * (1.0f / (float)B_N));
    }
}

extern "C" void kernel_launch(void* const* d_in, const int* in_sizes, int n_in,
                              void* d_out, int out_size, void* d_ws, size_t ws_size,
                              hipStream_t stream) {
    const float* hs  = (const float*)d_in[0];
    const float* w1  = (const float*)d_in[1];
    const float* b1v = (const float*)d_in[2];
    const float* w2  = (const float*)d_in[3];
    const float* b2v = (const float*)d_in[4];
    const float* w3  = (const float*)d_in[5];
    const float* b3v = (const float*)d_in[6];
    const int* groups = (const int*)d_in[7];
    const int* labels = (const int*)d_in[8];
    float* out = (float*)d_out;

    hipMemsetAsync(out, 0, sizeof(float), stream);
    ce_fused<<<B_N / SPB, 512, 0, stream>>>(hs, w1, b1v, w2, b2v, w3, b3v,
                                            groups, labels, out);
}